// Round 9
// baseline (511.201 us; speedup 1.0000x reference)
//
#include <hip/hip_runtime.h>
#include <math.h>

typedef unsigned short u16;
typedef __attribute__((ext_vector_type(8))) short bf16x8;   // 8 bf16 = 4 VGPRs
typedef __attribute__((ext_vector_type(4))) float f32x4;
typedef __attribute__((ext_vector_type(16))) float f32x16;

static constexpr int kN = 10000;
static constexpr int kNpad = 10240;       // 40 * 256 rows per relation range
static constexpr int kD = 1024;
static constexpr int kR = 8;
static constexpr int kE = 80000;
static constexpr int kKz = 2 * kD;        // 2048 : [u | x]
static constexpr int kCrows = kNpad * (kR + 1);  // 92160 compact y_c rows (worst case)
static constexpr int kTilesY = kCrows / 256;     // 360

#define GLB(p) ((const __attribute__((address_space(1))) unsigned int*)(const void*)(p))
#define LDSP(p) ((__attribute__((address_space(3))) unsigned int*)(p))

__device__ __forceinline__ u16 f2bf(float f) {
    union { float f; unsigned int i; } c; c.f = f;
    unsigned int u = c.i;
    return (u16)((u + 0x7FFFu + ((u >> 16) & 1u)) >> 16);   // RNE
}
__device__ __forceinline__ float bf2f(u16 u) {
    union { unsigned int i; float f; } c; c.i = ((unsigned int)u) << 16;
    return c.f;
}
__device__ __forceinline__ ushort4 f2bf4(float4 v) {
    ushort4 o; o.x = f2bf(v.x); o.y = f2bf(v.y); o.z = f2bf(v.z); o.w = f2bf(v.w);
    return o;
}

__global__ void zero16(uint4* __restrict__ p, long n16) {
    long i = (long)blockIdx.x * blockDim.x + threadIdx.x;
    long st = (long)gridDim.x * blockDim.x;
    uint4 z = make_uint4(0, 0, 0, 0);
    for (; i < n16; i += st) p[i] = z;
}

// Per edge: histogram dst (for CSR) and flag (rel, src) presence.
__global__ void mark_edges(const int* __restrict__ src, const int* __restrict__ dst,
                           const int* __restrict__ etype,
                           int* __restrict__ cntd, int* __restrict__ flag) {
    int e = blockIdx.x * blockDim.x + threadIdx.x;
    if (e < kE) {
        atomicAdd(&cntd[dst[e]], 1);
        flag[etype[e] * kN + src[e]] = 1;   // idempotent plain store
    }
}

// 10 blocks x 1024 thr.
//  blocks 0..7 : per-relation exclusive scan of flags -> compact row list + pos + count
//  block  8    : identity map for root range
//  block  9    : exclusive scan of cntd -> rowptr, zero cursor
__global__ __launch_bounds__(1024) void build_meta(const int* __restrict__ flag,
                                                   const int* __restrict__ cntd,
                                                   int* __restrict__ row_src,
                                                   int* __restrict__ pos_tab,
                                                   int* __restrict__ relcnt9,
                                                   int* __restrict__ rowptr,
                                                   int* __restrict__ cursor) {
    const int tid = threadIdx.x;
    if (blockIdx.x == kR) {   // root range: identity
        for (int i = tid; i < kNpad; i += 1024) row_src[i] = i;
        if (tid == 0) relcnt9[0] = kN;
        return;
    }
    const int lane = tid & 63;
    const int w = tid >> 6;
    __shared__ int wsum[16];
    __shared__ int carry;
    if (tid == 0) carry = 0;

    if (blockIdx.x == kR + 1) {   // rowptr scan
        const int nchunk = (kN + 1024) / 1024;
        for (int ch = 0; ch < nchunk; ++ch) {
            int idx = ch * 1024 + tid;
            int v = (idx < kN) ? cntd[idx] : 0;
            int s = v;
#pragma unroll
            for (int off = 1; off < 64; off <<= 1) {
                int t = __shfl_up(s, off, 64);
                if (lane >= off) s += t;
            }
            if (lane == 63) wsum[w] = s;
            __syncthreads();
            if (w == 0 && lane < 16) {
                int t = wsum[lane];
#pragma unroll
                for (int off = 1; off < 16; off <<= 1) {
                    int tt = __shfl_up(t, off, 64);
                    if (lane >= off) t += tt;
                }
                wsum[lane] = t;
            }
            __syncthreads();
            int wpre = (w > 0) ? wsum[w - 1] : 0;
            int incl = s + wpre + carry;
            int excl = incl - v;
            if (idx <= kN) rowptr[idx] = excl;
            if (idx < kN) cursor[idx] = 0;
            __syncthreads();
            if (tid == 1023) carry = incl;
            __syncthreads();
        }
        return;
    }

    const int r = blockIdx.x;   // 0..7: compact relation r
    const int base = kNpad * (r + 1);
    const int nchunk = (kN + 1023) / 1024;
    for (int ch = 0; ch < nchunk; ++ch) {
        int idx = ch * 1024 + tid;
        int v = (idx < kN) ? flag[r * kN + idx] : 0;
        int s = v;
#pragma unroll
        for (int off = 1; off < 64; off <<= 1) {
            int t = __shfl_up(s, off, 64);
            if (lane >= off) s += t;
        }
        if (lane == 63) wsum[w] = s;
        __syncthreads();
        if (w == 0 && lane < 16) {
            int t = wsum[lane];
#pragma unroll
            for (int off = 1; off < 16; off <<= 1) {
                int tt = __shfl_up(t, off, 64);
                if (lane >= off) t += tt;
            }
            wsum[lane] = t;
        }
        __syncthreads();
        int wpre = (w > 0) ? wsum[w - 1] : 0;
        int incl = s + wpre + carry;
        int excl = incl - v;
        if (idx < kN && v) {
            row_src[base + excl] = idx;
            pos_tab[r * kN + idx] = base + excl;
        }
        __syncthreads();
        if (tid == 1023) carry = incl;
        __syncthreads();
    }
    if (tid == 0) relcnt9[r + 1] = carry;
}

// erec = (y_c row << 3) | rel, CSR-grouped by dst.
__global__ void fill_edges(const int* __restrict__ src, const int* __restrict__ dst,
                           const int* __restrict__ etype, const int* __restrict__ rowptr,
                           int* __restrict__ cursor, const int* __restrict__ pos_tab,
                           int* __restrict__ erec) {
    int e = blockIdx.x * blockDim.x + threadIdx.x;
    if (e < kE) {
        int d = dst[e], r = etype[e], s = src[e];
        int pos = rowptr[d] + atomicAdd(&cursor[d], 1);
        erec[pos] = (pos_tab[r * kN + s] << 3) | r;
    }
}

// rows < kN: x fp32 -> bf16 into ga[:,1024:2048]; rows >= kN: zero both halves.
__global__ void cvt_x(const float* __restrict__ x, u16* __restrict__ ga) {
    int row = blockIdx.x;
    int c = threadIdx.x << 2;
    if (row < kN) {
        float4 v = *reinterpret_cast<const float4*>(x + (size_t)row * kD + c);
        *reinterpret_cast<ushort4*>(ga + (size_t)row * kKz + kD + c) = f2bf4(v);
    } else {
        ushort4 z = {0, 0, 0, 0};
        *reinterpret_cast<ushort4*>(ga + (size_t)row * kKz + c) = z;
        *reinterpret_cast<ushort4*>(ga + (size_t)row * kKz + kD + c) = z;
    }
}

// S [rows][cols] fp32 -> D[n*ldD + k] = S[k, n] bf16. Batched square blocks.
__global__ void transpose_to_bf16(const float* __restrict__ S, u16* __restrict__ D,
                                  int rows, int cols, int ldD) {
    S += (size_t)blockIdx.z * rows * cols;
    D += (size_t)blockIdx.z * rows * cols;
    __shared__ float t[32][33];
    int c0 = blockIdx.x * 32, r0 = blockIdx.y * 32;
    int x = threadIdx.x, y = threadIdx.y;   // block (32,8)
#pragma unroll
    for (int i = 0; i < 32; i += 8)
        t[y + i][x] = S[(size_t)(r0 + y + i) * cols + c0 + x];
    __syncthreads();
#pragma unroll
    for (int i = 0; i < 32; i += 8)
        D[(size_t)(c0 + y + i) * ldD + r0 + x] = f2bf(t[x][y + i]);
}

// One block (256 thr) per dst row: u[d] = y_c[d] + bias + sum_e rs[rel]*y_c[pos].
// Writes u bf16 into ga[:,0:1024].
__global__ __launch_bounds__(256) void aggregate(const u16* __restrict__ yc,
                                                 const float* __restrict__ bias,
                                                 const int* __restrict__ rowptr,
                                                 const int* __restrict__ erec,
                                                 u16* __restrict__ ga) {
    const int d = blockIdx.x;
    const int c = threadIdx.x << 2;
    const int e0 = rowptr[d], e1 = rowptr[d + 1];

    __shared__ float rs[kR];
    if (threadIdx.x == 0) {
        int cc[kR] = {0, 0, 0, 0, 0, 0, 0, 0};
        for (int e = e0; e < e1; ++e) cc[erec[e] & 7]++;
#pragma unroll
        for (int r = 0; r < kR; ++r) rs[r] = 1.0f / fmaxf((float)cc[r], 1.0f);
    }
    __syncthreads();

    ushort4 rv = *reinterpret_cast<const ushort4*>(yc + (size_t)d * kD + c);
    float4 bv = *reinterpret_cast<const float4*>(bias + c);
    float4 acc = make_float4(bf2f(rv.x) + bv.x, bf2f(rv.y) + bv.y,
                             bf2f(rv.z) + bv.z, bf2f(rv.w) + bv.w);

    for (int e = e0; e < e1; ++e) {
        int rec = erec[e];              // uniform across block
        int rel = rec & 7;
        int pos = rec >> 3;
        float sc = rs[rel];             // LDS broadcast
        ushort4 v = *reinterpret_cast<const ushort4*>(yc + (size_t)pos * kD + c);
        acc.x += sc * bf2f(v.x); acc.y += sc * bf2f(v.y);
        acc.z += sc * bf2f(v.z); acc.w += sc * bf2f(v.w);
    }
    *reinterpret_cast<ushort4*>(ga + (size_t)d * kKz + c) = f2bf4(acc);
}

// GEMM1 (compacted, 32x32x16 MFMA): y_c[grow] = x_bf[row_src[grow]] @ W_{rel}^T.
// Block tile 256x128, BK=32, 4 waves (each 128x64 = 4x2 tiles of 32x32).
// Operand-swapped mfma(B,A): lane holds C[row = lane&31]
// [col = 8*(reg>>2) + 4*(lane>>5) + (reg&3)]  (derived from m101 layout).
__global__ __launch_bounds__(256, 2) void gemm_compact(
    const u16* __restrict__ xb, int ldx,
    const u16* __restrict__ Bt9,
    const int* __restrict__ row_src, const int* __restrict__ relcnt9,
    u16* __restrict__ yc)
{
    const int t = blockIdx.y;
    const int relidx = t / 40;
    const int lt = t - relidx * 40;
    if (lt * 256 >= relcnt9[relidx]) return;   // uniform early-exit (before barriers)

    __shared__ u16 sA[256 * 32];
    __shared__ u16 sB[128 * 32];

    const int tid = threadIdx.x;
    const int wave = tid >> 6;
    const int lane = tid & 63;

    const int row0 = t * 256;
    const int col0 = blockIdx.x * 128;

    const int srow4 = lane >> 2;       // 0..15
    const int scol = (lane & 3) * 8;   // 16B chunk

    // A staging: gather rows via row_src (per-lane global addr; LDS dest lane-ordered)
    const u16* gA[4];
    u16* lA[4];
#pragma unroll
    for (int q = 0; q < 4; ++q) {
        int r = wave * 64 + q * 16;
        int srcrow = row_src[row0 + r + srow4];
        gA[q] = xb + (size_t)srcrow * ldx + scol;
        lA[q] = sA + r * 32;
    }
    const u16* gB[2];
    u16* lB[2];
#pragma unroll
    for (int p = 0; p < 2; ++p) {
        int r = p * 64 + wave * 16;
        gB[p] = Bt9 + (size_t)(relidx * kD + col0 + r + srow4) * kD + scol;
        lB[p] = sB + r * 32;
    }

    const int mq = (wave >> 1) * 128;  // wave row-half
    const int nq = (wave & 1) * 64;    // wave col-half
    const int fm = lane & 31;          // 32x32 operand: index within 32
    const int fk = (lane >> 5) * 8;    // k offset (8 contiguous)

    f32x16 acc[4][2];
#pragma unroll
    for (int i = 0; i < 4; ++i)
#pragma unroll
        for (int j = 0; j < 2; ++j)
#pragma unroll
            for (int r = 0; r < 16; ++r) acc[i][j][r] = 0.0f;

    for (int k0 = 0; k0 < kD; k0 += 32) {
        __syncthreads();
#pragma unroll
        for (int q = 0; q < 4; ++q)
            __builtin_amdgcn_global_load_lds(GLB(gA[q]), LDSP(lA[q]), 16, 0, 0);
#pragma unroll
        for (int p = 0; p < 2; ++p)
            __builtin_amdgcn_global_load_lds(GLB(gB[p]), LDSP(lB[p]), 16, 0, 0);
#pragma unroll
        for (int q = 0; q < 4; ++q) gA[q] += 32;
#pragma unroll
        for (int p = 0; p < 2; ++p) gB[p] += 32;
        __syncthreads();

        bf16x8 af[4][2], bfr[2][2];
#pragma unroll
        for (int s = 0; s < 2; ++s) {
#pragma unroll
            for (int i = 0; i < 4; ++i)
                af[i][s] = *reinterpret_cast<const bf16x8*>(
                    &sA[(mq + i * 32 + fm) * 32 + s * 16 + fk]);
#pragma unroll
            for (int j = 0; j < 2; ++j)
                bfr[j][s] = *reinterpret_cast<const bf16x8*>(
                    &sB[(nq + j * 32 + fm) * 32 + s * 16 + fk]);
        }
#pragma unroll
        for (int s = 0; s < 2; ++s)
#pragma unroll
            for (int i = 0; i < 4; ++i)
#pragma unroll
                for (int j = 0; j < 2; ++j)
                    acc[i][j] = __builtin_amdgcn_mfma_f32_32x32x16_bf16(
                        bfr[j][s], af[i][s], acc[i][j], 0, 0, 0);
    }

    // Swapped 32x32 C/D: row = lane&31 (per i-tile), col = 8*(reg>>2)+4*(lane>>5)+(reg&3)
    const int half4 = (lane >> 5) * 4;
#pragma unroll
    for (int i = 0; i < 4; ++i) {
        int row = row0 + mq + i * 32 + fm;   // y_c fully padded: no guard
#pragma unroll
        for (int j = 0; j < 2; ++j) {
            int colb = col0 + nq + j * 32 + half4;
#pragma unroll
            for (int g = 0; g < 4; ++g) {
                int col = colb + 8 * g;
                ushort4 o;
                o.x = f2bf(acc[i][j][4 * g + 0]);
                o.y = f2bf(acc[i][j][4 * g + 1]);
                o.z = f2bf(acc[i][j][4 * g + 2]);
                o.w = f2bf(acc[i][j][4 * g + 3]);
                *reinterpret_cast<ushort4*>(yc + (size_t)row * kD + col) = o;
            }
        }
    }
}

// GEMM2: 128x128 tile, BK=32, 4 waves, wave 64x64 (16x16x32, operand-swapped).
// z = A @ Bt^T + bias; h = tanh(u)*z + x*(1-z) -> Cf (fused combine).
__global__ __launch_bounds__(256) void gemm_mfma_gate(
    const u16* __restrict__ A, int lda,
    const u16* __restrict__ Bt, int ldb, int K,
    int M, const float* __restrict__ bias,
    float* __restrict__ Cf, const u16* __restrict__ uga, const float* __restrict__ xo)
{
    __shared__ u16 sA[128 * 32];
    __shared__ u16 sB[128 * 32];

    const int tid = threadIdx.x;
    const int wave = tid >> 6;
    const int lane = tid & 63;

    const int row0 = blockIdx.y * 128;
    const int col0 = blockIdx.x * 128;

    const int srow = wave * 16 + (lane >> 2);
    const int scol = (lane & 3) * 8;

    const u16* gA0 = A + (size_t)(row0 + srow) * lda + scol;
    const u16* gA1 = A + (size_t)(row0 + 64 + srow) * lda + scol;
    const u16* gB0 = Bt + (size_t)(col0 + srow) * ldb + scol;
    const u16* gB1 = Bt + (size_t)(col0 + 64 + srow) * ldb + scol;

    u16* lA0 = sA + (wave * 16) * 32;
    u16* lA1 = sA + (64 + wave * 16) * 32;
    u16* lB0 = sB + (wave * 16) * 32;
    u16* lB1 = sB + (64 + wave * 16) * 32;

    const int mq = (wave >> 1) * 64;
    const int nq = (wave & 1) * 64;
    const int fm = lane & 15;
    const int fk = (lane >> 4) * 8;

    f32x4 zf = {0.0f, 0.0f, 0.0f, 0.0f};
    f32x4 acc[4][4];
#pragma unroll
    for (int i = 0; i < 4; ++i)
#pragma unroll
        for (int j = 0; j < 4; ++j) acc[i][j] = zf;

    for (int k0 = 0; k0 < K; k0 += 32) {
        __syncthreads();
        __builtin_amdgcn_global_load_lds(GLB(gA0), LDSP(lA0), 16, 0, 0);
        __builtin_amdgcn_global_load_lds(GLB(gA1), LDSP(lA1), 16, 0, 0);
        __builtin_amdgcn_global_load_lds(GLB(gB0), LDSP(lB0), 16, 0, 0);
        __builtin_amdgcn_global_load_lds(GLB(gB1), LDSP(lB1), 16, 0, 0);
        gA0 += 32; gA1 += 32; gB0 += 32; gB1 += 32;
        __syncthreads();

        bf16x8 af[4], bfr[4];
#pragma unroll
        for (int i = 0; i < 4; ++i)
            af[i] = *reinterpret_cast<const bf16x8*>(&sA[(mq + i * 16 + fm) * 32 + fk]);
#pragma unroll
        for (int j = 0; j < 4; ++j)
            bfr[j] = *reinterpret_cast<const bf16x8*>(&sB[(nq + j * 16 + fm) * 32 + fk]);
#pragma unroll
        for (int i = 0; i < 4; ++i)
#pragma unroll
            for (int j = 0; j < 4; ++j)
                acc[i][j] = __builtin_amdgcn_mfma_f32_16x16x32_bf16(bfr[j], af[i], acc[i][j], 0, 0, 0);
    }

    const int cq = (lane >> 4) * 4;
#pragma unroll
    for (int i = 0; i < 4; ++i) {
        int row = row0 + mq + i * 16 + fm;
        if (row >= M) continue;
#pragma unroll
        for (int j = 0; j < 4; ++j) {
            int col = col0 + nq + j * 16 + cq;
            f32x4 v = acc[i][j];
            float4 bv = *reinterpret_cast<const float4*>(bias + col);
            v[0] += bv.x; v[1] += bv.y; v[2] += bv.z; v[3] += bv.w;
            ushort4 ur = *reinterpret_cast<const ushort4*>(uga + (size_t)row * kKz + col);
            float4 xr = *reinterpret_cast<const float4*>(xo + (size_t)row * kD + col);
            float4 h;
            h.x = tanhf(bf2f(ur.x)) * v[0] + xr.x * (1.0f - v[0]);
            h.y = tanhf(bf2f(ur.y)) * v[1] + xr.y * (1.0f - v[1]);
            h.z = tanhf(bf2f(ur.z)) * v[2] + xr.z * (1.0f - v[2]);
            h.w = tanhf(bf2f(ur.w)) * v[3] + xr.w * (1.0f - v[3]);
            *reinterpret_cast<float4*>(Cf + (size_t)row * kD + col) = h;
        }
    }
}

extern "C" void kernel_launch(void* const* d_in, const int* in_sizes, int n_in,
                              void* d_out, int out_size, void* d_ws, size_t ws_size,
                              hipStream_t stream) {
    (void)in_sizes; (void)n_in; (void)out_size; (void)ws_size;

    const float* x     = (const float*)d_in[0];
    const int* eidx    = (const int*)d_in[1];
    const int* etype   = (const int*)d_in[2];
    const float* weight= (const float*)d_in[3];
    const float* root  = (const float*)d_in[4];
    const float* bias  = (const float*)d_in[5];
    const float* wgate = (const float*)d_in[6];
    const float* bgate = (const float*)d_in[7];
    float* out = (float*)d_out;

    const int* src = eidx;
    const int* dst = eidx + kE;

    // ---- workspace ----
    char* ws = (char*)d_ws;
    size_t off = 0;
    u16* yc   = (u16*)(ws + off);    off += (size_t)kCrows * kD * 2;   // 188.7 MB
    u16* ga   = (u16*)(ws + off);    off += (size_t)kNpad * kKz * 2;   //  41.9 MB
    u16* Bt9  = (u16*)(ws + off);    off += (size_t)(kR + 1) * kD * kD * 2; // 18.9 MB
    u16* wg_t = (u16*)(ws + off);    off += (size_t)kD * kKz * 2;      //   4.2 MB
    int* cntd    = (int*)(ws + off); off += (size_t)kN * 4;
    int* flag    = (int*)(ws + off); off += (size_t)kR * kN * 4;
    int* row_src = (int*)(ws + off); off += (size_t)kCrows * 4;
    int* pos_tab = (int*)(ws + off); off += (size_t)kR * kN * 4;
    int* rowp    = (int*)(ws + off); off += (size_t)(kN + 16) * 4;
    int* curs    = (int*)(ws + off); off += (size_t)kN * 4;
    int* erec    = (int*)(ws + off); off += (size_t)kE * 4;
    int* relcnt9 = (int*)(ws + off); off += 16 * 4;

    // zero cntd+flag+row_src in one pass (contiguous)
    zero16<<<180, 256, 0, stream>>>((uint4*)cntd, (long)(kN + kR * kN + kCrows) / 4);

    mark_edges<<<(kE + 255) / 256, 256, 0, stream>>>(src, dst, etype, cntd, flag);
    build_meta<<<kR + 2, 1024, 0, stream>>>(flag, cntd, row_src, pos_tab, relcnt9,
                                            rowp, curs);
    fill_edges<<<(kE + 255) / 256, 256, 0, stream>>>(src, dst, etype, rowp, curs,
                                                     pos_tab, erec);

    // x -> bf16 into ga[:,1024:2048]; zero padding rows of both halves
    cvt_x<<<kNpad, 256, 0, stream>>>(x, ga);

    // Bt9[n,k]: rows [0,1024) root^T; rows [1024(1+r),..) W_r^T. wg_t[n,k]=wgate[k,n].
    {
        dim3 b(32, 8);
        transpose_to_bf16<<<dim3(kD / 32, kD / 32, 1), b, 0, stream>>>(root, Bt9, kD, kD, kD);
        transpose_to_bf16<<<dim3(kD / 32, kD / 32, kR), b, 0, stream>>>(
            weight, Bt9 + (size_t)kD * kD, kD, kD, kD);
        transpose_to_bf16<<<dim3(kD / 32, kKz / 32, 1), b, 0, stream>>>(wgate, wg_t, kKz, kD, kKz);
    }

    // GEMM1 (compacted): y_c = gathered x rows @ per-relation W
    dim3 g1(kD / 128, kTilesY);   // 8 x 360, ~1/3 exit early
    gemm_compact<<<g1, 256, 0, stream>>>(ga + kD, kKz, Bt9, row_src, relcnt9, yc);

    // aggregate: u -> ga[:,0:1024] (bf16)
    aggregate<<<kN, 256, 0, stream>>>(yc, bias, rowp, erec, ga);

    // GEMM2: z = ga @ wg_t + b_gate; h = tanh(u)*z + x*(1-z) -> out
    dim3 g2(kD / 128, kNpad / 128);    // 8 x 80
    gemm_mfma_gate<<<g2, 256, 0, stream>>>(ga, kKz, wg_t, kKz, kKz, kN, bgate, out, ga, x);
}